// Round 1
// baseline (8590.056 us; speedup 1.0000x reference)
//
#include <hip/hip_runtime.h>
#include <hip/hip_bf16.h>

// Neural CDE, B=256 T=512 D=64 H=128 W=256.
// Design (round 1): one fused kernel launch per scan step (512 launches).
//  - grid 256 WGs = 8 batch-groups (32 rows) x 32 HD-chunks (256 cols = 4 h).
//  - stage A (gemm0+gemm1+softplus) computed redundantly per WG (avoids intra-step sync).
//  - gemm2 chunk + tanh + d-contraction + y update, y state stays f32 in global (ping-pong).
//  - weights pre-converted to bf16 once (prep kernel); MFMA 16x16x32 bf16, f32 accum.
// dt = 1, frac = 0 for k<=510 => deriv = coeffs_b[:,k]; k=511 => b+2c+3d at idx 510.

#define BB 256
#define DD 64
#define HH 128
#define WW 256
#define HD 8192
#define TSTEPS 512
#define PAD_Y 152   // 128+24 bf16: row stride 304B = 19*16 (aligned), banks spread
#define PAD_G 280   // 256+24 bf16: row stride 560B = 35*16

typedef __bf16 bf16x8 __attribute__((ext_vector_type(8)));
typedef float f32x4 __attribute__((ext_vector_type(4)));

__device__ __forceinline__ float softplus_f(float x) {
  return (x > 15.f) ? x : __logf(1.f + __expf(x));
}
__device__ __forceinline__ float tanh_f(float x) {
  float e = __expf(2.f * x);
  return 1.f - 2.f / (e + 1.f);
}

__global__ void prep_kernel(const float* __restrict__ w0, const float* __restrict__ w1,
                            const float* __restrict__ w2,
                            __bf16* __restrict__ w0b, __bf16* __restrict__ w1b,
                            __bf16* __restrict__ w2b) {
  int stride = gridDim.x * blockDim.x;
  int i0 = blockIdx.x * blockDim.x + threadIdx.x;
  for (int i = i0; i < WW * HH; i += stride) w0b[i] = (__bf16)w0[i];
  for (int i = i0; i < WW * WW; i += stride) w1b[i] = (__bf16)w1[i];
  for (int i = i0; i < HD * WW; i += stride) w2b[i] = (__bf16)w2[i];
}

// y0 = MLP(coeffs_a[:,0,:]) in plain f32 (one-off, tiny)
__global__ __launch_bounds__(256) void init_kernel(
    const float* __restrict__ ca, const float* __restrict__ iw0, const float* __restrict__ ib0,
    const float* __restrict__ iw1, const float* __restrict__ ib1,
    const float* __restrict__ iw2, const float* __restrict__ ib2,
    float* __restrict__ y0) {
  __shared__ float x0[DD];
  __shared__ float h0[WW];
  __shared__ float h1[WW];
  int b = blockIdx.x, t = threadIdx.x;
  if (t < DD) x0[t] = ca[((size_t)b * 511) * DD + t];
  __syncthreads();
  float a = ib0[t];
  for (int d = 0; d < DD; ++d) a = fmaf(x0[d], iw0[t * DD + d], a);
  h0[t] = fmaxf(a, 0.f);
  __syncthreads();
  a = ib1[t];
  for (int d = 0; d < WW; ++d) a = fmaf(h0[d], iw1[t * WW + d], a);
  h1[t] = fmaxf(a, 0.f);
  __syncthreads();
  if (t < HH) {
    a = ib2[t];
    for (int d = 0; d < WW; ++d) a = fmaf(h1[d], iw2[t * WW + d], a);
    y0[b * HH + t] = a;
  }
}

// One scan step. 512 threads = 8 waves. WG = (group grp: rows rb..rb+31, chunk j: HD cols c0..c0+255).
// Wave wv owns 32 output cols [wv*32, wv*32+32) of each 256-col GEMM; for gemm2, wave pair
// (2h, 2h+1) covers one h (64 d's), partials combined through LDS.
__global__ __launch_bounds__(512) void step_kernel(
    const __bf16* __restrict__ w0b, const __bf16* __restrict__ w1b, const __bf16* __restrict__ w2b,
    const float* __restrict__ fb0, const float* __restrict__ fb1, const float* __restrict__ fb2,
    const float* __restrict__ cbp, const float* __restrict__ ccp, const float* __restrict__ cdp,
    const float* __restrict__ y_in, float* __restrict__ y_out, int k)
{
  __shared__ __align__(16) __bf16 yb[32 * PAD_Y];
  __shared__ __align__(16) __bf16 g0s[32 * PAD_G];
  __shared__ __align__(16) __bf16 g1s[32 * PAD_G];
  __shared__ float dv[32 * DD];
  __shared__ float pbuf[8 * 32];

  const int tid = threadIdx.x;
  const int wv = tid >> 6;
  const int l = tid & 63;
  const int l16 = l & 15;
  const int lq = l >> 4;

  const int wid = blockIdx.x;
  const int grp = wid >> 5;
  const int j = wid & 31;
  const int rb = grp * 32;   // batch row base
  const int c0 = j * 256;    // HD col base

  // stage y (f32 global -> bf16 LDS) for MFMA A-operand
  for (int i = tid; i < 32 * HH; i += 512) {
    int r = i >> 7, h = i & (HH - 1);
    yb[r * PAD_Y + h] = (__bf16)y_in[(rb + r) * HH + h];
  }
  // stage deriv for this step
  {
    int kk = (k <= 510) ? k : 510;
    for (int i = tid; i < 32 * DD; i += 512) {
      int r = i >> 6, d = i & (DD - 1);
      int off = ((rb + r) * 511 + kk) * DD + d;
      float v = cbp[off];
      if (k == 511) v += 2.f * ccp[off] + 3.f * cdp[off];
      dv[i] = v;
    }
  }
  __syncthreads();

  // ---- gemm0: g0 = softplus(y(32x128) @ w0^T + b0), cols [wv*32, wv*32+32)
  {
    f32x4 acc[2][2] = {};
    #pragma unroll
    for (int kb = 0; kb < 4; ++kb) {
      bf16x8 afr0 = *(const bf16x8*)&yb[(l16) * PAD_Y + kb * 32 + lq * 8];
      bf16x8 afr1 = *(const bf16x8*)&yb[(16 + l16) * PAD_Y + kb * 32 + lq * 8];
      #pragma unroll
      for (int n = 0; n < 2; ++n) {
        int col = wv * 32 + n * 16 + l16;
        bf16x8 bfr = *(const bf16x8*)&w0b[col * HH + kb * 32 + lq * 8];
        acc[0][n] = __builtin_amdgcn_mfma_f32_16x16x32_bf16(afr0, bfr, acc[0][n], 0, 0, 0);
        acc[1][n] = __builtin_amdgcn_mfma_f32_16x16x32_bf16(afr1, bfr, acc[1][n], 0, 0, 0);
      }
    }
    #pragma unroll
    for (int n = 0; n < 2; ++n) {
      int col = wv * 32 + n * 16 + l16;
      float bias = fb0[col];
      #pragma unroll
      for (int m = 0; m < 2; ++m)
        #pragma unroll
        for (int r = 0; r < 4; ++r)
          g0s[(m * 16 + lq * 4 + r) * PAD_G + col] = (__bf16)softplus_f(acc[m][n][r] + bias);
    }
  }
  __syncthreads();

  // ---- gemm1: g1 = softplus(g0(32x256) @ w1^T + b1)
  {
    f32x4 acc[2][2] = {};
    #pragma unroll
    for (int kb = 0; kb < 8; ++kb) {
      bf16x8 afr0 = *(const bf16x8*)&g0s[(l16) * PAD_G + kb * 32 + lq * 8];
      bf16x8 afr1 = *(const bf16x8*)&g0s[(16 + l16) * PAD_G + kb * 32 + lq * 8];
      #pragma unroll
      for (int n = 0; n < 2; ++n) {
        int col = wv * 32 + n * 16 + l16;
        bf16x8 bfr = *(const bf16x8*)&w1b[col * WW + kb * 32 + lq * 8];
        acc[0][n] = __builtin_amdgcn_mfma_f32_16x16x32_bf16(afr0, bfr, acc[0][n], 0, 0, 0);
        acc[1][n] = __builtin_amdgcn_mfma_f32_16x16x32_bf16(afr1, bfr, acc[1][n], 0, 0, 0);
      }
    }
    #pragma unroll
    for (int n = 0; n < 2; ++n) {
      int col = wv * 32 + n * 16 + l16;
      float bias = fb1[col];
      #pragma unroll
      for (int m = 0; m < 2; ++m)
        #pragma unroll
        for (int r = 0; r < 4; ++r)
          g1s[(m * 16 + lq * 4 + r) * PAD_G + col] = (__bf16)softplus_f(acc[m][n][r] + bias);
    }
  }
  __syncthreads();

  // ---- gemm2 chunk + tanh + contraction over d
  {
    f32x4 acc[2][2] = {};
    #pragma unroll
    for (int kb = 0; kb < 8; ++kb) {
      bf16x8 afr0 = *(const bf16x8*)&g1s[(l16) * PAD_G + kb * 32 + lq * 8];
      bf16x8 afr1 = *(const bf16x8*)&g1s[(16 + l16) * PAD_G + kb * 32 + lq * 8];
      #pragma unroll
      for (int n = 0; n < 2; ++n) {
        int col = wv * 32 + n * 16 + l16;
        bf16x8 bfr = *(const bf16x8*)&w2b[(size_t)(c0 + col) * WW + kb * 32 + lq * 8];
        acc[0][n] = __builtin_amdgcn_mfma_f32_16x16x32_bf16(afr0, bfr, acc[0][n], 0, 0, 0);
        acc[1][n] = __builtin_amdgcn_mfma_f32_16x16x32_bf16(afr1, bfr, acc[1][n], 0, 0, 0);
      }
    }
    float p[2][4] = {};
    #pragma unroll
    for (int n = 0; n < 2; ++n) {
      int col = wv * 32 + n * 16 + l16;
      float bias = fb2[c0 + col];
      int d = (wv & 1) * 32 + n * 16 + l16;   // d-index within this h
      #pragma unroll
      for (int m = 0; m < 2; ++m) {
        int rbase = m * 16 + lq * 4;
        #pragma unroll
        for (int r = 0; r < 4; ++r) {
          float f = tanh_f(acc[m][n][r] + bias);
          p[m][r] = fmaf(f, dv[(rbase + r) * DD + d], p[m][r]);
        }
      }
    }
    // reduce across the 16 lanes of each quarter (summing 16 cols -> per-row partial)
    #pragma unroll
    for (int off = 1; off < 16; off <<= 1)
      #pragma unroll
      for (int m = 0; m < 2; ++m)
        #pragma unroll
        for (int r = 0; r < 4; ++r)
          p[m][r] += __shfl_xor(p[m][r], off);
    if (l16 == 0) {
      #pragma unroll
      for (int m = 0; m < 2; ++m)
        #pragma unroll
        for (int r = 0; r < 4; ++r)
          pbuf[wv * 32 + m * 16 + lq * 4 + r] = p[m][r];
    }
  }
  __syncthreads();

  // combine wave pairs (each h covered by waves 2h,2h+1) and update y (f32 state)
  if (tid < 128) {
    int hl = tid >> 5, r = tid & 31;
    int brow = rb + r, h = j * 4 + hl;
    float v = pbuf[(2 * hl) * 32 + r] + pbuf[(2 * hl + 1) * 32 + r];
    y_out[brow * HH + h] = y_in[brow * HH + h] + v;  // dt = 1
  }
}

__global__ __launch_bounds__(256) void final_kernel(const float* __restrict__ y,
                                                    const float* __restrict__ lw,
                                                    const float* __restrict__ lb,
                                                    float* __restrict__ out) {
  int b = threadIdx.x;
  float a = lb[0];
  for (int h = 0; h < HH; ++h) a = fmaf(y[b * HH + h], lw[h], a);
  out[b] = 1.f / (1.f + __expf(-a));
}

extern "C" void kernel_launch(void* const* d_in, const int* in_sizes, int n_in,
                              void* d_out, int out_size, void* d_ws, size_t ws_size,
                              hipStream_t stream) {
  const float* cdp = (const float*)d_in[1];
  const float* ccp = (const float*)d_in[2];
  const float* cbp = (const float*)d_in[3];
  const float* cap = (const float*)d_in[4];
  const float* iw0 = (const float*)d_in[5];
  const float* ib0 = (const float*)d_in[6];
  const float* iw1 = (const float*)d_in[7];
  const float* ib1 = (const float*)d_in[8];
  const float* iw2 = (const float*)d_in[9];
  const float* ib2 = (const float*)d_in[10];
  const float* fw0 = (const float*)d_in[11];
  const float* fb0 = (const float*)d_in[12];
  const float* fw1 = (const float*)d_in[13];
  const float* fb1 = (const float*)d_in[14];
  const float* fw2 = (const float*)d_in[15];
  const float* fb2 = (const float*)d_in[16];
  const float* lw  = (const float*)d_in[17];
  const float* lb  = (const float*)d_in[18];

  char* ws = (char*)d_ws;
  __bf16* w0b = (__bf16*)(ws);
  __bf16* w1b = (__bf16*)(ws + 65536);
  __bf16* w2b = (__bf16*)(ws + 65536 + 131072);
  float* yA = (float*)(ws + 65536 + 131072 + 4194304);
  float* yB = (float*)(ws + 65536 + 131072 + 4194304 + 131072);

  prep_kernel<<<512, 256, 0, stream>>>(fw0, fw1, fw2, w0b, w1b, w2b);
  init_kernel<<<BB, 256, 0, stream>>>(cap, iw0, ib0, iw1, ib1, iw2, ib2, yA);
  float* bufs[2] = {yA, yB};
  for (int k = 0; k < TSTEPS; ++k) {
    step_kernel<<<256, 512, 0, stream>>>(w0b, w1b, w2b, fb0, fb1, fb2,
                                         cbp, ccp, cdp,
                                         bufs[k & 1], bufs[(k + 1) & 1], k);
  }
  final_kernel<<<1, 256, 0, stream>>>(bufs[0], lw, lb, (float*)d_out);

  (void)in_sizes; (void)n_in; (void)out_size; (void)ws_size;
}

// Round 2
// 5435.303 us; speedup vs baseline: 1.5804x; 1.5804x over previous
//
#include <hip/hip_runtime.h>
#include <hip/hip_bf16.h>

// Neural CDE, B=256 T=512 D=64 H=128 W=256.
// Round 2: persistent kernel — all 512 scan steps in ONE launch.
//  - grid 256 WGs = 8 batch-groups (32 rows) x 32 HD-chunks (256 cols = 4 h), 1 WG/CU.
//  - weights held in per-wave REGISTERS (40 bf16x8 frags) across the whole scan.
//  - per-group (32 WG) barrier per step via step-indexed device-scope counters.
//  - y state ping-pongs in global via agent-scope cache-bypassing atomics (LLC-coherent).
// dt = 1, frac = 0 for k<=510 => deriv = coeffs_b[:,k]; k=511 => b+2c+3d at idx 510.

#define BB 256
#define DD 64
#define HH 128
#define WW 256
#define HD 8192
#define TSTEPS 512
#define PAD_Y 152   // 128+24 bf16
#define PAD_G 280   // 256+24 bf16

typedef __bf16 bf16x8 __attribute__((ext_vector_type(8)));
typedef float f32x4 __attribute__((ext_vector_type(4)));

__device__ __forceinline__ float softplus_f(float x) {
  return (x > 15.f) ? x : __logf(1.f + __expf(x));
}
__device__ __forceinline__ float tanh_f(float x) {
  float e = __expf(2.f * x);
  return 1.f - 2.f / (e + 1.f);
}

__global__ void prep_kernel(const float* __restrict__ w0, const float* __restrict__ w1,
                            const float* __restrict__ w2,
                            __bf16* __restrict__ w0b, __bf16* __restrict__ w1b,
                            __bf16* __restrict__ w2b) {
  int stride = gridDim.x * blockDim.x;
  int i0 = blockIdx.x * blockDim.x + threadIdx.x;
  for (int i = i0; i < WW * HH; i += stride) w0b[i] = (__bf16)w0[i];
  for (int i = i0; i < WW * WW; i += stride) w1b[i] = (__bf16)w1[i];
  for (int i = i0; i < HD * WW; i += stride) w2b[i] = (__bf16)w2[i];
}

// y0 = MLP(coeffs_a[:,0,:]) in plain f32 (one-off, tiny)
__global__ __launch_bounds__(256) void init_kernel(
    const float* __restrict__ ca, const float* __restrict__ iw0, const float* __restrict__ ib0,
    const float* __restrict__ iw1, const float* __restrict__ ib1,
    const float* __restrict__ iw2, const float* __restrict__ ib2,
    float* __restrict__ y0) {
  __shared__ float x0[DD];
  __shared__ float h0[WW];
  __shared__ float h1[WW];
  int b = blockIdx.x, t = threadIdx.x;
  if (t < DD) x0[t] = ca[((size_t)b * 511) * DD + t];
  __syncthreads();
  float a = ib0[t];
  for (int d = 0; d < DD; ++d) a = fmaf(x0[d], iw0[t * DD + d], a);
  h0[t] = fmaxf(a, 0.f);
  __syncthreads();
  a = ib1[t];
  for (int d = 0; d < WW; ++d) a = fmaf(h0[d], iw1[t * WW + d], a);
  h1[t] = fmaxf(a, 0.f);
  __syncthreads();
  if (t < HH) {
    a = ib2[t];
    for (int d = 0; d < WW; ++d) a = fmaf(h1[d], iw2[t * WW + d], a);
    y0[b * HH + t] = a;
  }
}

// Persistent step kernel: 256 WGs x 512 threads, loops k=0..511 internally.
__global__ __launch_bounds__(512, 2) void step_persist(
    const __bf16* __restrict__ w0b, const __bf16* __restrict__ w1b, const __bf16* __restrict__ w2b,
    const float* __restrict__ fb0, const float* __restrict__ fb1, const float* __restrict__ fb2,
    const float* __restrict__ cbp, const float* __restrict__ ccp, const float* __restrict__ cdp,
    float* __restrict__ yA, float* __restrict__ yB, int* __restrict__ ctr)
{
  __shared__ __align__(16) __bf16 yb[32 * PAD_Y];
  __shared__ __align__(16) __bf16 g0s[32 * PAD_G];
  __shared__ __align__(16) __bf16 g1s[32 * PAD_G];
  __shared__ float dv[32 * DD];
  __shared__ float pbuf[8 * 32];

  const int tid = threadIdx.x;
  const int wv = tid >> 6;
  const int l = tid & 63;
  const int l16 = l & 15;
  const int lq = l >> 4;

  const int wid = blockIdx.x;
  const int grp = wid >> 5;
  const int j = wid & 31;
  const int rb = grp * 32;   // batch row base
  const int c0 = j * 256;    // HD col base

  // ---- load loop-invariant weight fragments into registers (held all 512 steps)
  bf16x8 w0f[4][2], w1f[8][2], w2f[8][2];
  #pragma unroll
  for (int n = 0; n < 2; ++n) {
    int col = wv * 32 + n * 16 + l16;
    #pragma unroll
    for (int kb = 0; kb < 4; ++kb)
      w0f[kb][n] = *(const bf16x8*)&w0b[col * HH + kb * 32 + lq * 8];
    #pragma unroll
    for (int kb = 0; kb < 8; ++kb)
      w1f[kb][n] = *(const bf16x8*)&w1b[col * WW + kb * 32 + lq * 8];
    #pragma unroll
    for (int kb = 0; kb < 8; ++kb)
      w2f[kb][n] = *(const bf16x8*)&w2b[(size_t)(c0 + col) * WW + kb * 32 + lq * 8];
  }
  const float bias0 = fb0[wv * 32 + 0 * 16 + l16];
  const float bias0b = fb0[wv * 32 + 1 * 16 + l16];
  const float bias1 = fb1[wv * 32 + 0 * 16 + l16];
  const float bias1b = fb1[wv * 32 + 1 * 16 + l16];
  const float bias2 = fb2[c0 + wv * 32 + 0 * 16 + l16];
  const float bias2b = fb2[c0 + wv * 32 + 1 * 16 + l16];

  const float* yr = yA;
  float* yw = yB;

  for (int k = 0; k < TSTEPS; ++k) {
    // ---- deriv loads into regs early (LLC latency hidden under staging+gemm0)
    float dreg[4];
    {
      int kk = (k <= 510) ? k : 510;
      #pragma unroll
      for (int q = 0; q < 4; ++q) {
        int i = tid + q * 512;
        int r = i >> 6, d = i & (DD - 1);
        int off = ((rb + r) * 511 + kk) * DD + d;
        float v = cbp[off];
        if (k == 511) v += 2.f * ccp[off] + 3.f * cdp[off];
        dreg[q] = v;
      }
    }
    // ---- stage y (LLC bypass loads -> bf16 LDS)
    #pragma unroll
    for (int q = 0; q < 8; ++q) {
      int i = tid + q * 512;
      int r = i >> 7, h = i & (HH - 1);
      float v = __hip_atomic_load((const float*)&yr[(rb + r) * HH + h],
                                  __ATOMIC_RELAXED, __HIP_MEMORY_SCOPE_AGENT);
      yb[r * PAD_Y + h] = (__bf16)v;
    }
    __syncthreads();

    // ---- gemm0: g0 = softplus(y(32x128) @ w0^T + b0)
    {
      f32x4 acc[2][2] = {};
      #pragma unroll
      for (int kb = 0; kb < 4; ++kb) {
        bf16x8 afr0 = *(const bf16x8*)&yb[(l16) * PAD_Y + kb * 32 + lq * 8];
        bf16x8 afr1 = *(const bf16x8*)&yb[(16 + l16) * PAD_Y + kb * 32 + lq * 8];
        #pragma unroll
        for (int n = 0; n < 2; ++n) {
          acc[0][n] = __builtin_amdgcn_mfma_f32_16x16x32_bf16(afr0, w0f[kb][n], acc[0][n], 0, 0, 0);
          acc[1][n] = __builtin_amdgcn_mfma_f32_16x16x32_bf16(afr1, w0f[kb][n], acc[1][n], 0, 0, 0);
        }
      }
      #pragma unroll
      for (int n = 0; n < 2; ++n) {
        int col = wv * 32 + n * 16 + l16;
        float bias = n ? bias0b : bias0;
        #pragma unroll
        for (int m = 0; m < 2; ++m)
          #pragma unroll
          for (int r = 0; r < 4; ++r)
            g0s[(m * 16 + lq * 4 + r) * PAD_G + col] = (__bf16)softplus_f(acc[m][n][r] + bias);
      }
    }
    // dv regs -> LDS (visible after next barrier, used in gemm2)
    #pragma unroll
    for (int q = 0; q < 4; ++q) dv[tid + q * 512] = dreg[q];
    __syncthreads();

    // ---- gemm1: g1 = softplus(g0(32x256) @ w1^T + b1)
    {
      f32x4 acc[2][2] = {};
      #pragma unroll
      for (int kb = 0; kb < 8; ++kb) {
        bf16x8 afr0 = *(const bf16x8*)&g0s[(l16) * PAD_G + kb * 32 + lq * 8];
        bf16x8 afr1 = *(const bf16x8*)&g0s[(16 + l16) * PAD_G + kb * 32 + lq * 8];
        #pragma unroll
        for (int n = 0; n < 2; ++n) {
          acc[0][n] = __builtin_amdgcn_mfma_f32_16x16x32_bf16(afr0, w1f[kb][n], acc[0][n], 0, 0, 0);
          acc[1][n] = __builtin_amdgcn_mfma_f32_16x16x32_bf16(afr1, w1f[kb][n], acc[1][n], 0, 0, 0);
        }
      }
      #pragma unroll
      for (int n = 0; n < 2; ++n) {
        int col = wv * 32 + n * 16 + l16;
        float bias = n ? bias1b : bias1;
        #pragma unroll
        for (int m = 0; m < 2; ++m)
          #pragma unroll
          for (int r = 0; r < 4; ++r)
            g1s[(m * 16 + lq * 4 + r) * PAD_G + col] = (__bf16)softplus_f(acc[m][n][r] + bias);
      }
    }
    __syncthreads();

    // ---- gemm2 chunk + tanh + contraction over d
    {
      f32x4 acc[2][2] = {};
      #pragma unroll
      for (int kb = 0; kb < 8; ++kb) {
        bf16x8 afr0 = *(const bf16x8*)&g1s[(l16) * PAD_G + kb * 32 + lq * 8];
        bf16x8 afr1 = *(const bf16x8*)&g1s[(16 + l16) * PAD_G + kb * 32 + lq * 8];
        #pragma unroll
        for (int n = 0; n < 2; ++n) {
          acc[0][n] = __builtin_amdgcn_mfma_f32_16x16x32_bf16(afr0, w2f[kb][n], acc[0][n], 0, 0, 0);
          acc[1][n] = __builtin_amdgcn_mfma_f32_16x16x32_bf16(afr1, w2f[kb][n], acc[1][n], 0, 0, 0);
        }
      }
      float p[2][4] = {};
      #pragma unroll
      for (int n = 0; n < 2; ++n) {
        float bias = n ? bias2b : bias2;
        int d = (wv & 1) * 32 + n * 16 + l16;   // d-index within this h
        #pragma unroll
        for (int m = 0; m < 2; ++m) {
          int rbase = m * 16 + lq * 4;
          #pragma unroll
          for (int r = 0; r < 4; ++r) {
            float f = tanh_f(acc[m][n][r] + bias);
            p[m][r] = fmaf(f, dv[(rbase + r) * DD + d], p[m][r]);
          }
        }
      }
      #pragma unroll
      for (int off = 1; off < 16; off <<= 1)
        #pragma unroll
        for (int m = 0; m < 2; ++m)
          #pragma unroll
          for (int r = 0; r < 4; ++r)
            p[m][r] += __shfl_xor(p[m][r], off);
      if (l16 == 0) {
        #pragma unroll
        for (int m = 0; m < 2; ++m)
          #pragma unroll
          for (int r = 0; r < 4; ++r)
            pbuf[wv * 32 + m * 16 + lq * 4 + r] = p[m][r];
      }
    }
    __syncthreads();

    // ---- combine wave pairs, update y (LLC bypass store)
    if (tid < 128) {
      int hl = tid >> 5, r = tid & 31;
      int brow = rb + r, h = j * 4 + hl;
      float v = pbuf[(2 * hl) * 32 + r] + pbuf[(2 * hl + 1) * 32 + r];
      float ycur = __hip_atomic_load((const float*)&yr[brow * HH + h],
                                     __ATOMIC_RELAXED, __HIP_MEMORY_SCOPE_AGENT);
      __hip_atomic_store(&yw[brow * HH + h], ycur + v,
                         __ATOMIC_RELAXED, __HIP_MEMORY_SCOPE_AGENT);
    }

    // ---- group barrier (32 WGs), step-indexed counter
    __syncthreads();   // drains all vmem (stores completed at agent scope) before arrival
    if (tid == 0) {
      int* c = &ctr[grp * TSTEPS + k];
      __hip_atomic_fetch_add(c, 1, __ATOMIC_RELEASE, __HIP_MEMORY_SCOPE_AGENT);
      int spins = 0;
      while (__hip_atomic_load(c, __ATOMIC_RELAXED, __HIP_MEMORY_SCOPE_AGENT) < 32) {
        if (++spins > (1 << 22)) break;   // structural deadlock impossible; bail visibly
        __builtin_amdgcn_s_sleep(2);
      }
    }
    __syncthreads();

    const float* t = yr; yr = yw; yw = (float*)t;
  }
}

__global__ __launch_bounds__(256) void final_kernel(const float* __restrict__ y,
                                                    const float* __restrict__ lw,
                                                    const float* __restrict__ lb,
                                                    float* __restrict__ out) {
  int b = threadIdx.x;
  float a = lb[0];
  for (int h = 0; h < HH; ++h) a = fmaf(y[b * HH + h], lw[h], a);
  out[b] = 1.f / (1.f + __expf(-a));
}

extern "C" void kernel_launch(void* const* d_in, const int* in_sizes, int n_in,
                              void* d_out, int out_size, void* d_ws, size_t ws_size,
                              hipStream_t stream) {
  const float* cdp = (const float*)d_in[1];
  const float* ccp = (const float*)d_in[2];
  const float* cbp = (const float*)d_in[3];
  const float* cap = (const float*)d_in[4];
  const float* iw0 = (const float*)d_in[5];
  const float* ib0 = (const float*)d_in[6];
  const float* iw1 = (const float*)d_in[7];
  const float* ib1 = (const float*)d_in[8];
  const float* iw2 = (const float*)d_in[9];
  const float* ib2 = (const float*)d_in[10];
  const float* fw0 = (const float*)d_in[11];
  const float* fb0 = (const float*)d_in[12];
  const float* fw1 = (const float*)d_in[13];
  const float* fb1 = (const float*)d_in[14];
  const float* fw2 = (const float*)d_in[15];
  const float* fb2 = (const float*)d_in[16];
  const float* lw  = (const float*)d_in[17];
  const float* lb  = (const float*)d_in[18];

  char* ws = (char*)d_ws;
  __bf16* w0b = (__bf16*)(ws);                              // 64 KB
  __bf16* w1b = (__bf16*)(ws + 65536);                      // 128 KB
  __bf16* w2b = (__bf16*)(ws + 65536 + 131072);             // 4 MB
  float* yA = (float*)(ws + 65536 + 131072 + 4194304);      // 128 KB
  float* yB = (float*)(ws + 65536 + 131072 + 4194304 + 131072);
  int* ctr  = (int*)(ws + 65536 + 131072 + 4194304 + 131072 + 131072);  // 16 KB

  hipMemsetAsync(ctr, 0, 8 * TSTEPS * sizeof(int), stream);
  prep_kernel<<<512, 256, 0, stream>>>(fw0, fw1, fw2, w0b, w1b, w2b);
  init_kernel<<<BB, 256, 0, stream>>>(cap, iw0, ib0, iw1, ib1, iw2, ib2, yA);
  step_persist<<<256, 512, 0, stream>>>(w0b, w1b, w2b, fb0, fb1, fb2,
                                        cbp, ccp, cdp, yA, yB, ctr);
  final_kernel<<<1, 256, 0, stream>>>(yA, lw, lb, (float*)d_out);

  (void)in_sizes; (void)n_in; (void)out_size; (void)ws_size;
}

// Round 3
// 4052.711 us; speedup vs baseline: 2.1196x; 1.3412x over previous
//
#include <hip/hip_runtime.h>
#include <hip/hip_bf16.h>
#include <stdint.h>

// Neural CDE, B=256 T=512 D=64 H=128 W=256.
// Round 3: persistent kernel + tagged bf16 push-exchange (no barrier, no counter).
//  - grid 256 WGs = 8 batch-groups (32 rows) x 32 HD-chunks (256 cols = 4 h), 1 WG/CU.
//  - f32 state lives in REGISTERS of the owning WG; published as (tag16|bf16) words.
//  - swapped-operand MFMA: output reg-dim = weight col -> vectorized LDS writes,
//    cheap d-reduction (2 shuffles), float4 dv reads.
// dt = 1, frac = 0 for k<=510 => deriv = coeffs_b[:,k]; k=511 => b+2c+3d at idx 510.

#define BB 256
#define DD 64
#define HH 128
#define WW 256
#define HD 8192
#define TSTEPS 512
#define PAD_Y 152   // bf16 row stride for yb
#define PAD_G 280   // bf16 row stride for g0s/g1s
#define PAD_DV 68   // f32 row stride for dv (68 mod 32 = 4 -> spreads banks)

typedef __bf16 bf16x8 __attribute__((ext_vector_type(8)));
typedef __bf16 bf16x4 __attribute__((ext_vector_type(4)));
typedef float f32x4 __attribute__((ext_vector_type(4)));

__device__ __forceinline__ float softplus_f(float x) {
  return (x > 15.f) ? x : __logf(1.f + __expf(x));
}
__device__ __forceinline__ float tanh_f(float x) {
  float e = __expf(2.f * x);
  return 1.f - 2.f / (e + 1.f);
}

__device__ __forceinline__ void publish_y(uint32_t* slot, int idx, float val, uint32_t tag) {
  unsigned short ub = __builtin_bit_cast(unsigned short, (__bf16)val);
  __hip_atomic_store(&slot[idx], (tag << 16) | (uint32_t)ub,
                     __ATOMIC_RELAXED, __HIP_MEMORY_SCOPE_AGENT);
}

__global__ void prep_kernel(const float* __restrict__ w0, const float* __restrict__ w1,
                            const float* __restrict__ w2,
                            __bf16* __restrict__ w0b, __bf16* __restrict__ w1b,
                            __bf16* __restrict__ w2b) {
  int stride = gridDim.x * blockDim.x;
  int i0 = blockIdx.x * blockDim.x + threadIdx.x;
  for (int i = i0; i < WW * HH; i += stride) w0b[i] = (__bf16)w0[i];
  for (int i = i0; i < WW * WW; i += stride) w1b[i] = (__bf16)w1[i];
  for (int i = i0; i < HD * WW; i += stride) w2b[i] = (__bf16)w2[i];
}

// y0 = MLP(coeffs_a[:,0,:]) in plain f32 (one-off, tiny)
__global__ __launch_bounds__(256) void init_kernel(
    const float* __restrict__ ca, const float* __restrict__ iw0, const float* __restrict__ ib0,
    const float* __restrict__ iw1, const float* __restrict__ ib1,
    const float* __restrict__ iw2, const float* __restrict__ ib2,
    float* __restrict__ y0) {
  __shared__ float x0[DD];
  __shared__ float h0[WW];
  __shared__ float h1[WW];
  int b = blockIdx.x, t = threadIdx.x;
  if (t < DD) x0[t] = ca[((size_t)b * 511) * DD + t];
  __syncthreads();
  float a = ib0[t];
  for (int d = 0; d < DD; ++d) a = fmaf(x0[d], iw0[t * DD + d], a);
  h0[t] = fmaxf(a, 0.f);
  __syncthreads();
  a = ib1[t];
  for (int d = 0; d < WW; ++d) a = fmaf(h0[d], iw1[t * WW + d], a);
  h1[t] = fmaxf(a, 0.f);
  __syncthreads();
  if (t < HH) {
    a = ib2[t];
    for (int d = 0; d < WW; ++d) a = fmaf(h1[d], iw2[t * WW + d], a);
    y0[b * HH + t] = a;
  }
}

// Persistent step kernel: 256 WGs x 512 threads, loops k=0..511 internally.
__global__ __launch_bounds__(512, 2) void step_persist(
    const __bf16* __restrict__ w0b, const __bf16* __restrict__ w1b, const __bf16* __restrict__ w2b,
    const float* __restrict__ fb0, const float* __restrict__ fb1, const float* __restrict__ fb2,
    const float* __restrict__ cbp, const float* __restrict__ ccp, const float* __restrict__ cdp,
    float* __restrict__ yA, uint32_t* __restrict__ pk)
{
  __shared__ __align__(16) __bf16 yb[32 * PAD_Y];
  __shared__ __align__(16) __bf16 g0s[32 * PAD_G];
  __shared__ __align__(16) __bf16 g1s[32 * PAD_G];
  __shared__ __align__(16) float dv[32 * PAD_DV];
  __shared__ float pbuf[8 * 32];

  const int tid = threadIdx.x;
  const int wv = tid >> 6;
  const int l = tid & 63;
  const int l16 = l & 15;
  const int lq = l >> 4;

  const int wid = blockIdx.x;
  const int grp = wid >> 5;
  const int j = wid & 31;
  const int rb = grp * 32;   // batch row base
  const int c0 = j * 256;    // HD col base

  // ---- loop-invariant weight fragments (A-operand role: lane l16 <-> weight col)
  bf16x8 w0f[4][2], w1f[8][2], w2f[8][2];
  #pragma unroll
  for (int c = 0; c < 2; ++c) {
    int col = wv * 32 + c * 16 + l16;
    #pragma unroll
    for (int kb = 0; kb < 4; ++kb)
      w0f[kb][c] = *(const bf16x8*)&w0b[col * HH + kb * 32 + lq * 8];
    #pragma unroll
    for (int kb = 0; kb < 8; ++kb)
      w1f[kb][c] = *(const bf16x8*)&w1b[col * WW + kb * 32 + lq * 8];
    #pragma unroll
    for (int kb = 0; kb < 8; ++kb)
      w2f[kb][c] = *(const bf16x8*)&w2b[(size_t)(c0 + col) * WW + kb * 32 + lq * 8];
  }
  // biases per output col-quad (reg dim): float4 at col = wv*32 + c*16 + lq*4
  f32x4 b0r[2], b1r[2], b2r[2];
  #pragma unroll
  for (int c = 0; c < 2; ++c) {
    b0r[c] = *(const f32x4*)&fb0[wv * 32 + c * 16 + lq * 4];
    b1r[c] = *(const f32x4*)&fb1[wv * 32 + c * 16 + lq * 4];
    b2r[c] = *(const f32x4*)&fb2[c0 + wv * 32 + c * 16 + lq * 4];
  }

  // ---- register-resident f32 state: thread tid<128 owns (row rb+(tid&31), h = 4j+(tid>>5))
  float yreg = 0.f;
  int myidx = 0;
  if (tid < 128) {
    int r = tid & 31, hl = tid >> 5;
    myidx = (rb + r) * HH + (4 * j + hl);
    yreg = yA[myidx];
    publish_y(pk, myidx, yreg, 1u);   // S_0 -> slot 0, tag 1
  }

  for (int k = 0; k < TSTEPS; ++k) {
    const uint32_t want = (uint32_t)(k + 1);
    const uint32_t* src = pk + (size_t)(k & 1) * (BB * HH);

    // ---- deriv loads into regs early
    float dreg[4];
    {
      int kk = (k <= 510) ? k : 510;
      #pragma unroll
      for (int q = 0; q < 4; ++q) {
        int i = tid + q * 512;
        int r = i >> 6, d = i & (DD - 1);
        int off = ((rb + r) * 511 + kk) * DD + d;
        float v = cbp[off];
        if (k == 511) v += 2.f * ccp[off] + 3.f * cdp[off];
        dreg[q] = v;
      }
    }

    // ---- poll + stage peers' y (tagged bf16 words)
    {
      uint32_t v[8];
      int ad[8];
      #pragma unroll
      for (int q = 0; q < 8; ++q) {
        int i = tid + q * 512;
        ad[q] = (rb + (i >> 7)) * HH + (i & (HH - 1));
        v[q] = __hip_atomic_load(&src[ad[q]], __ATOMIC_RELAXED, __HIP_MEMORY_SCOPE_AGENT);
      }
      int spins = 0;
      bool allok;
      do {
        allok = true;
        #pragma unroll
        for (int q = 0; q < 8; ++q) {
          if ((v[q] >> 16) != want) {
            allok = false;
            v[q] = __hip_atomic_load(&src[ad[q]], __ATOMIC_RELAXED, __HIP_MEMORY_SCOPE_AGENT);
          }
        }
        if (!allok) {
          __builtin_amdgcn_s_sleep(1);
          if (++spins > (1 << 20)) break;   // structurally impossible; bail visibly
        }
      } while (!allok);
      #pragma unroll
      for (int q = 0; q < 8; ++q) {
        int i = tid + q * 512;
        yb[(i >> 7) * PAD_Y + (i & (HH - 1))] =
            __builtin_bit_cast(__bf16, (unsigned short)(v[q] & 0xFFFFu));
      }
    }
    __syncthreads();

    // ---- gemm0 (swapped): D[w0col, brow] = w0 . y
    {
      f32x4 acc[2][2] = {};
      #pragma unroll
      for (int kb = 0; kb < 4; ++kb) {
        bf16x8 y0 = *(const bf16x8*)&yb[l16 * PAD_Y + kb * 32 + lq * 8];
        bf16x8 y1 = *(const bf16x8*)&yb[(16 + l16) * PAD_Y + kb * 32 + lq * 8];
        #pragma unroll
        for (int c = 0; c < 2; ++c) {
          acc[c][0] = __builtin_amdgcn_mfma_f32_16x16x32_bf16(w0f[kb][c], y0, acc[c][0], 0, 0, 0);
          acc[c][1] = __builtin_amdgcn_mfma_f32_16x16x32_bf16(w0f[kb][c], y1, acc[c][1], 0, 0, 0);
        }
      }
      #pragma unroll
      for (int c = 0; c < 2; ++c)
        #pragma unroll
        for (int bt = 0; bt < 2; ++bt) {
          bf16x4 o;
          #pragma unroll
          for (int r = 0; r < 4; ++r)
            o[r] = (__bf16)softplus_f(acc[c][bt][r] + b0r[c][r]);
          *(bf16x4*)&g0s[(bt * 16 + l16) * PAD_G + wv * 32 + c * 16 + lq * 4] = o;
        }
    }
    // dv regs -> LDS (read in gemm2 after barrier 3)
    #pragma unroll
    for (int q = 0; q < 4; ++q) {
      int i = tid + q * 512;
      dv[(i >> 6) * PAD_DV + (i & (DD - 1))] = dreg[q];
    }
    __syncthreads();

    // ---- gemm1 (swapped): D[w1col, brow] = w1 . g0
    {
      f32x4 acc[2][2] = {};
      #pragma unroll
      for (int kb = 0; kb < 8; ++kb) {
        bf16x8 a0 = *(const bf16x8*)&g0s[l16 * PAD_G + kb * 32 + lq * 8];
        bf16x8 a1 = *(const bf16x8*)&g0s[(16 + l16) * PAD_G + kb * 32 + lq * 8];
        #pragma unroll
        for (int c = 0; c < 2; ++c) {
          acc[c][0] = __builtin_amdgcn_mfma_f32_16x16x32_bf16(w1f[kb][c], a0, acc[c][0], 0, 0, 0);
          acc[c][1] = __builtin_amdgcn_mfma_f32_16x16x32_bf16(w1f[kb][c], a1, acc[c][1], 0, 0, 0);
        }
      }
      #pragma unroll
      for (int c = 0; c < 2; ++c)
        #pragma unroll
        for (int bt = 0; bt < 2; ++bt) {
          bf16x4 o;
          #pragma unroll
          for (int r = 0; r < 4; ++r)
            o[r] = (__bf16)softplus_f(acc[c][bt][r] + b1r[c][r]);
          *(bf16x4*)&g1s[(bt * 16 + l16) * PAD_G + wv * 32 + c * 16 + lq * 4] = o;
        }
    }
    __syncthreads();

    // ---- gemm2 chunk (swapped) + tanh + d-contraction
    {
      f32x4 acc[2][2] = {};
      #pragma unroll
      for (int kb = 0; kb < 8; ++kb) {
        bf16x8 a0 = *(const bf16x8*)&g1s[l16 * PAD_G + kb * 32 + lq * 8];
        bf16x8 a1 = *(const bf16x8*)&g1s[(16 + l16) * PAD_G + kb * 32 + lq * 8];
        #pragma unroll
        for (int c = 0; c < 2; ++c) {
          acc[c][0] = __builtin_amdgcn_mfma_f32_16x16x32_bf16(w2f[kb][c], a0, acc[c][0], 0, 0, 0);
          acc[c][1] = __builtin_amdgcn_mfma_f32_16x16x32_bf16(w2f[kb][c], a1, acc[c][1], 0, 0, 0);
        }
      }
      // lane holds: batch row = bt*16+l16; d = (wv&1)*32 + c*16 + lq*4 + r
      #pragma unroll
      for (int bt = 0; bt < 2; ++bt) {
        float p = 0.f;
        #pragma unroll
        for (int c = 0; c < 2; ++c) {
          f32x4 dvv = *(const f32x4*)&dv[(bt * 16 + l16) * PAD_DV +
                                         (wv & 1) * 32 + c * 16 + lq * 4];
          #pragma unroll
          for (int r = 0; r < 4; ++r) {
            float f = tanh_f(acc[c][bt][r] + b2r[c][r]);
            p = fmaf(f, dvv[r], p);
          }
        }
        p += __shfl_xor(p, 16);
        p += __shfl_xor(p, 32);
        if (l < 16) pbuf[wv * 32 + bt * 16 + l] = p;
      }
    }
    __syncthreads();

    // ---- combine wave pairs (d halves), update register state, publish
    if (tid < 128) {
      int hl = tid >> 5, r = tid & 31;
      yreg += pbuf[(2 * hl) * 32 + r] + pbuf[(2 * hl + 1) * 32 + r];
      publish_y(pk + (size_t)((k + 1) & 1) * (BB * HH), myidx, yreg, (uint32_t)(k + 2));
    }
    __syncthreads();
  }

  // final f32 state -> yA (kernel-end flush makes it visible to final_kernel)
  if (tid < 128) yA[myidx] = yreg;
}

__global__ __launch_bounds__(256) void final_kernel(const float* __restrict__ y,
                                                    const float* __restrict__ lw,
                                                    const float* __restrict__ lb,
                                                    float* __restrict__ out) {
  int b = threadIdx.x;
  float a = lb[0];
  for (int h = 0; h < HH; ++h) a = fmaf(y[b * HH + h], lw[h], a);
  out[b] = 1.f / (1.f + __expf(-a));
}

extern "C" void kernel_launch(void* const* d_in, const int* in_sizes, int n_in,
                              void* d_out, int out_size, void* d_ws, size_t ws_size,
                              hipStream_t stream) {
  const float* cdp = (const float*)d_in[1];
  const float* ccp = (const float*)d_in[2];
  const float* cbp = (const float*)d_in[3];
  const float* cap = (const float*)d_in[4];
  const float* iw0 = (const float*)d_in[5];
  const float* ib0 = (const float*)d_in[6];
  const float* iw1 = (const float*)d_in[7];
  const float* ib1 = (const float*)d_in[8];
  const float* iw2 = (const float*)d_in[9];
  const float* ib2 = (const float*)d_in[10];
  const float* fw0 = (const float*)d_in[11];
  const float* fb0 = (const float*)d_in[12];
  const float* fw1 = (const float*)d_in[13];
  const float* fb1 = (const float*)d_in[14];
  const float* fw2 = (const float*)d_in[15];
  const float* fb2 = (const float*)d_in[16];
  const float* lw  = (const float*)d_in[17];
  const float* lb  = (const float*)d_in[18];

  char* ws = (char*)d_ws;
  __bf16* w0b = (__bf16*)(ws);                              // 64 KB
  __bf16* w1b = (__bf16*)(ws + 65536);                      // 128 KB
  __bf16* w2b = (__bf16*)(ws + 65536 + 131072);             // 4 MB
  float* yA = (float*)(ws + 65536 + 131072 + 4194304);      // 128 KB
  uint32_t* pk = (uint32_t*)(ws + 65536 + 131072 + 4194304 + 131072);  // 256 KB (2 slots)

  hipMemsetAsync(pk, 0, 2 * BB * HH * sizeof(uint32_t), stream);
  prep_kernel<<<512, 256, 0, stream>>>(fw0, fw1, fw2, w0b, w1b, w2b);
  init_kernel<<<BB, 256, 0, stream>>>(cap, iw0, ib0, iw1, ib1, iw2, ib2, yA);
  step_persist<<<256, 512, 0, stream>>>(w0b, w1b, w2b, fb0, fb1, fb2,
                                        cbp, ccp, cdp, yA, pk);
  final_kernel<<<1, 256, 0, stream>>>(yA, lw, lb, (float*)d_out);

  (void)in_sizes; (void)n_in; (void)out_size; (void)ws_size;
}